// Round 1
// baseline (2373.847 us; speedup 1.0000x reference)
//
#include <hip/hip_runtime.h>

#define HSZ 64
#define ISZ 8
#define TSZ 512

__device__ __forceinline__ float fast_rcp(float x) { return __builtin_amdgcn_rcpf(x); }
__device__ __forceinline__ float sigm(float x) { return fast_rcp(1.0f + __expf(-x)); }
__device__ __forceinline__ float tanh_fast(float x) {
    // tanh(x) = 2*sigmoid(2x) - 1
    return fmaf(2.0f, fast_rcp(1.0f + __expf(-2.0f * x)), -1.0f);
}

// One wave (64 lanes) per batch element. Lane j owns gate rows {j, 64+j, 128+j, 192+j}.
// W_hh rows live in registers (fully unrolled, compile-time indexed). h exchanged via LDS.
__global__ __launch_bounds__(64, 1) void lstm_fused(
    const float* __restrict__ x,      // [B, T, I]
    const float* __restrict__ W_ih,   // [4H, I]
    const float* __restrict__ W_hh,   // [4H, H]
    const float* __restrict__ b_ih,   // [4H]
    const float* __restrict__ b_hh,   // [4H]
    const float* __restrict__ W_fc,   // [O, H] with O=1
    const float* __restrict__ b_fc,   // [O]
    float* __restrict__ out)          // [B, O]
{
    const int b = blockIdx.x;
    const int j = threadIdx.x;  // 0..63

    // ---- load per-lane weights into registers ----
    float whh[4][HSZ];   // whh[g][k] = W_hh[g*64 + j][k]
    float wih[4][ISZ];
    float bias[4];
#pragma unroll
    for (int g = 0; g < 4; ++g) {
        const int row = g * HSZ + j;
#pragma unroll
        for (int k = 0; k < HSZ; k += 4) {
            const float4 v = *reinterpret_cast<const float4*>(&W_hh[row * HSZ + k]);
            whh[g][k + 0] = v.x; whh[g][k + 1] = v.y;
            whh[g][k + 2] = v.z; whh[g][k + 3] = v.w;
        }
#pragma unroll
        for (int i = 0; i < ISZ; i += 4) {
            const float4 v = *reinterpret_cast<const float4*>(&W_ih[row * ISZ + i]);
            wih[g][i + 0] = v.x; wih[g][i + 1] = v.y;
            wih[g][i + 2] = v.z; wih[g][i + 3] = v.w;
        }
        bias[g] = b_ih[row] + b_hh[row];
    }

    __shared__ float h_sh[HSZ];
    __shared__ float x_sh[64 * ISZ];  // 64 timesteps of x, 2 KB

    h_sh[j] = 0.0f;
    float c = 0.0f, h = 0.0f;
    __syncthreads();

    const float* xb = x + (size_t)b * TSZ * ISZ;

    for (int t = 0; t < TSZ; ++t) {
        // ---- stage 64 timesteps of x into LDS (coalesced) ----
        if ((t & 63) == 0) {
            __syncthreads();  // WAR on x_sh (first iter harmless)
            const float4* src = reinterpret_cast<const float4*>(xb + (size_t)t * ISZ);
            reinterpret_cast<float4*>(x_sh)[j]      = src[j];
            reinterpret_cast<float4*>(x_sh)[j + 64] = src[j + 64];
            __syncthreads();
        }

        // ---- x contribution: 4 gates x 8 inputs ----
        const float* xt = &x_sh[(t & 63) * ISZ];
        float a0 = bias[0], a1 = bias[1], a2 = bias[2], a3 = bias[3];
#pragma unroll
        for (int i = 0; i < ISZ; ++i) {
            const float xv = xt[i];  // uniform-address LDS broadcast
            a0 = fmaf(xv, wih[0][i], a0);
            a1 = fmaf(xv, wih[1][i], a1);
            a2 = fmaf(xv, wih[2][i], a2);
            a3 = fmaf(xv, wih[3][i], a3);
        }

        // ---- recurrent matvec: 4 gates x 64 h, weights in VGPRs ----
#pragma unroll
        for (int k = 0; k < HSZ; k += 4) {
            const float4 hv = *reinterpret_cast<const float4*>(&h_sh[k]);  // broadcast
            a0 = fmaf(hv.x, whh[0][k + 0], a0);
            a1 = fmaf(hv.x, whh[1][k + 0], a1);
            a2 = fmaf(hv.x, whh[2][k + 0], a2);
            a3 = fmaf(hv.x, whh[3][k + 0], a3);
            a0 = fmaf(hv.y, whh[0][k + 1], a0);
            a1 = fmaf(hv.y, whh[1][k + 1], a1);
            a2 = fmaf(hv.y, whh[2][k + 1], a2);
            a3 = fmaf(hv.y, whh[3][k + 1], a3);
            a0 = fmaf(hv.z, whh[0][k + 2], a0);
            a1 = fmaf(hv.z, whh[1][k + 2], a1);
            a2 = fmaf(hv.z, whh[2][k + 2], a2);
            a3 = fmaf(hv.z, whh[3][k + 2], a3);
            a0 = fmaf(hv.w, whh[0][k + 3], a0);
            a1 = fmaf(hv.w, whh[1][k + 3], a1);
            a2 = fmaf(hv.w, whh[2][k + 3], a2);
            a3 = fmaf(hv.w, whh[3][k + 3], a3);
        }

        // ---- activations + state update (torch gate order i,f,g,o) ----
        const float ig = sigm(a0);
        const float fg = sigm(a1);
        const float gg = tanh_fast(a2);
        const float og = sigm(a3);
        c = fmaf(fg, c, ig * gg);
        h = og * tanh_fast(c);

        __syncthreads();        // all lanes done reading old h_sh
        h_sh[j] = h;
        __syncthreads();        // new h visible
    }

    // ---- final FC: out[b] = sum_j h_j * W_fc[j] + b_fc ----
    float p = h * W_fc[j];
#pragma unroll
    for (int off = 32; off > 0; off >>= 1) p += __shfl_down(p, off);
    if (j == 0) out[b] = p + b_fc[0];
}

extern "C" void kernel_launch(void* const* d_in, const int* in_sizes, int n_in,
                              void* d_out, int out_size, void* d_ws, size_t ws_size,
                              hipStream_t stream) {
    const float* x    = (const float*)d_in[0];
    const float* W_ih = (const float*)d_in[1];
    const float* W_hh = (const float*)d_in[2];
    const float* b_ih = (const float*)d_in[3];
    const float* b_hh = (const float*)d_in[4];
    const float* W_fc = (const float*)d_in[5];
    const float* b_fc = (const float*)d_in[6];
    float* out = (float*)d_out;

    const int B = in_sizes[0] / (TSZ * ISZ);  // 4096
    lstm_fused<<<B, 64, 0, stream>>>(x, W_ih, W_hh, b_ih, b_hh, W_fc, b_fc, out);
}

// Round 2
// 406.453 us; speedup vs baseline: 5.8404x; 5.8404x over previous
//
#include <hip/hip_runtime.h>

#define HSZ 64
#define ISZ 8
#define TSZ 512
#define BTILE 16   // batch rows per block
#define NW 4       // waves per block
#define KPAD 104   // 96 K-positions used + 8 pad (bank spread)

typedef __attribute__((ext_vector_type(8))) short bf16x8;
typedef __attribute__((ext_vector_type(4))) float f32x4;
typedef unsigned short u16;

__device__ __forceinline__ u16 bf16_rne(float f) {
    union { float f; unsigned int u; } v; v.f = f;
    unsigned int r = v.u + 0x7FFF + ((v.u >> 16) & 1);
    return (u16)(r >> 16);
}
__device__ __forceinline__ float bf16f(u16 s) {
    union { unsigned int u; float f; } v; v.u = ((unsigned int)s) << 16;
    return v.f;
}
__device__ __forceinline__ float sigm(float x) {
    return __builtin_amdgcn_rcpf(1.0f + __builtin_amdgcn_exp2f(-1.442695041f * x));
}
__device__ __forceinline__ float tanh_(float x) {
    return fmaf(2.0f, __builtin_amdgcn_rcpf(1.0f + __builtin_amdgcn_exp2f(-2.885390082f * x)), -1.0f);
}

// block = 16 batch rows, 4 waves. Wave w owns hidden units [16w,16w+16):
// gate cols {g*64 + 16w + 0..15} for g in {i,f,g,o}. Recurrent+input matvec via
// mfma_f32_16x16x32_bf16 with split-bf16 (hi+lo) A and B: 3-term product.
// A (shared, LDS, double-buffered): [batch 16][K], K = 64 h | 8 x | 24 zero-pad.
__global__ __launch_bounds__(256, 1) void lstm_mfma(
    const float* __restrict__ x,      // [B, T, I]
    const float* __restrict__ W_ih,   // [4H, I]
    const float* __restrict__ W_hh,   // [4H, H]
    const float* __restrict__ b_ih,   // [4H]
    const float* __restrict__ b_hh,   // [4H]
    const float* __restrict__ W_fc,   // [O, H]
    const float* __restrict__ b_fc,   // [O]
    float* __restrict__ out)          // [B, O]
{
    const int tid = threadIdx.x;
    const int w  = tid >> 6;   // wave 0..3
    const int l  = tid & 63;
    const int lr = l & 15;     // A-row / B-col / D-col lane index
    const int lg = l >> 4;     // k-group
    const int B0 = blockIdx.x * BTILE;

    __shared__ __align__(16) u16 A_lds[2][2][BTILE][KPAD];  // [buf][hi/lo][row][k]
    __shared__ float red[NW][BTILE];

    // zero all of A_lds (zero pad region stays zero forever; h(0)=0)
    for (int i = tid; i < 2 * 2 * BTILE * KPAD; i += 256)
        ((u16*)A_lds)[i] = 0;

    // ---- B fragments (weights, hi/lo) into registers ----
    bf16x8 bhi[4][3], blo[4][3];
#pragma unroll
    for (int g = 0; g < 4; ++g) {
        const int row = g * HSZ + w * 16 + lr;  // gate row in [0,256)
#pragma unroll
        for (int kt = 0; kt < 3; ++kt) {
            float wv[8];
            if (kt < 2) {
                const float4 a = *reinterpret_cast<const float4*>(&W_hh[row * HSZ + kt * 32 + lg * 8]);
                const float4 b = *reinterpret_cast<const float4*>(&W_hh[row * HSZ + kt * 32 + lg * 8 + 4]);
                wv[0] = a.x; wv[1] = a.y; wv[2] = a.z; wv[3] = a.w;
                wv[4] = b.x; wv[5] = b.y; wv[6] = b.z; wv[7] = b.w;
            } else if (lg == 0) {   // k = 64..71 -> W_ih row
                const float4 a = *reinterpret_cast<const float4*>(&W_ih[row * ISZ]);
                const float4 b = *reinterpret_cast<const float4*>(&W_ih[row * ISZ + 4]);
                wv[0] = a.x; wv[1] = a.y; wv[2] = a.z; wv[3] = a.w;
                wv[4] = b.x; wv[5] = b.y; wv[6] = b.z; wv[7] = b.w;
            } else {                // k = 72..95 -> zero pad
#pragma unroll
                for (int j = 0; j < 8; ++j) wv[j] = 0.0f;
            }
#pragma unroll
            for (int j = 0; j < 8; ++j) {
                const u16 hi = bf16_rne(wv[j]);
                bhi[g][kt][j] = (short)hi;
                blo[g][kt][j] = (short)bf16_rne(wv[j] - bf16f(hi));
            }
        }
    }
    float bias[4];
#pragma unroll
    for (int g = 0; g < 4; ++g)
        bias[g] = b_ih[g * HSZ + w * 16 + lr] + b_hh[g * HSZ + w * 16 + lr];

    __syncthreads();  // zeroing visible before x staging

    // stage x(0) into buf 0 (wave 0): lane -> batch l>>2, input pair (l&3)*2
    const int rb = l >> 2, ip = (l & 3) * 2;
    if (w == 0) {
        const float2 xv = *reinterpret_cast<const float2*>(&x[((size_t)(B0 + rb) * TSZ + 0) * ISZ + ip]);
        const u16 h0 = bf16_rne(xv.x), h1 = bf16_rne(xv.y);
        A_lds[0][0][rb][HSZ + ip]     = h0;
        A_lds[0][1][rb][HSZ + ip]     = bf16_rne(xv.x - bf16f(h0));
        A_lds[0][0][rb][HSZ + ip + 1] = h1;
        A_lds[0][1][rb][HSZ + ip + 1] = bf16_rne(xv.y - bf16f(h1));
    }
    __syncthreads();

    float c[4]  = {0.f, 0.f, 0.f, 0.f};
    float hv[4] = {0.f, 0.f, 0.f, 0.f};

    for (int t = 0; t < TSZ; ++t) {
        const int buf = t & 1, bufn = buf ^ 1;

        // prefetch x(t+1) early (hidden under MFMA + activations)
        float2 xv = {0.f, 0.f};
        if (w == 0 && t + 1 < TSZ)
            xv = *reinterpret_cast<const float2*>(&x[((size_t)(B0 + rb) * TSZ + t + 1) * ISZ + ip]);

        // A fragments: lane reads row lr, k = kt*32 + lg*8 .. +7 (16B, ~conflict-free)
        bf16x8 ahi[3], alo[3];
#pragma unroll
        for (int kt = 0; kt < 3; ++kt) {
            ahi[kt] = *reinterpret_cast<const bf16x8*>(&A_lds[buf][0][lr][kt * 32 + lg * 8]);
            alo[kt] = *reinterpret_cast<const bf16x8*>(&A_lds[buf][1][lr][kt * 32 + lg * 8]);
        }

        f32x4 acc[4];
#pragma unroll
        for (int g = 0; g < 4; ++g) acc[g] = f32x4{bias[g], bias[g], bias[g], bias[g]};
#pragma unroll
        for (int g = 0; g < 4; ++g) {
#pragma unroll
            for (int kt = 0; kt < 3; ++kt) {
                acc[g] = __builtin_amdgcn_mfma_f32_16x16x32_bf16(ahi[kt], bhi[g][kt], acc[g], 0, 0, 0);
                acc[g] = __builtin_amdgcn_mfma_f32_16x16x32_bf16(alo[kt], bhi[g][kt], acc[g], 0, 0, 0);
                acc[g] = __builtin_amdgcn_mfma_f32_16x16x32_bf16(ahi[kt], blo[g][kt], acc[g], 0, 0, 0);
            }
        }

        // activations: lane owns (batch row = lg*4+r, hidden col = 16w+lr)
#pragma unroll
        for (int r = 0; r < 4; ++r) {
            const float ig = sigm(acc[0][r]);
            const float fg = sigm(acc[1][r]);
            const float gg = tanh_(acc[2][r]);
            const float og = sigm(acc[3][r]);
            c[r]  = fmaf(fg, c[r], ig * gg);
            hv[r] = og * tanh_(c[r]);
            const u16 hh = bf16_rne(hv[r]);
            const int row = lg * 4 + r;
            A_lds[bufn][0][row][w * 16 + lr] = hh;
            A_lds[bufn][1][row][w * 16 + lr] = bf16_rne(hv[r] - bf16f(hh));
        }

        // store prefetched x(t+1)
        if (w == 0 && t + 1 < TSZ) {
            const u16 h0 = bf16_rne(xv.x), h1 = bf16_rne(xv.y);
            A_lds[bufn][0][rb][HSZ + ip]     = h0;
            A_lds[bufn][1][rb][HSZ + ip]     = bf16_rne(xv.x - bf16f(h0));
            A_lds[bufn][0][rb][HSZ + ip + 1] = h1;
            A_lds[bufn][1][rb][HSZ + ip + 1] = bf16_rne(xv.y - bf16f(h1));
        }
        __syncthreads();
    }

    // ---- final FC: out[b] = sum_hidden h * W_fc + b_fc ----
    const float wfc = W_fc[w * 16 + lr];
#pragma unroll
    for (int r = 0; r < 4; ++r) {
        float v = hv[r] * wfc;
        v += __shfl_xor(v, 1);
        v += __shfl_xor(v, 2);
        v += __shfl_xor(v, 4);
        v += __shfl_xor(v, 8);
        if (lr == 0) red[w][lg * 4 + r] = v;  // sum over this wave's 16 hidden
    }
    __syncthreads();
    if (tid < BTILE)
        out[B0 + tid] = red[0][tid] + red[1][tid] + red[2][tid] + red[3][tid] + b_fc[0];
}

extern "C" void kernel_launch(void* const* d_in, const int* in_sizes, int n_in,
                              void* d_out, int out_size, void* d_ws, size_t ws_size,
                              hipStream_t stream) {
    const float* x    = (const float*)d_in[0];
    const float* W_ih = (const float*)d_in[1];
    const float* W_hh = (const float*)d_in[2];
    const float* b_ih = (const float*)d_in[3];
    const float* b_hh = (const float*)d_in[4];
    const float* W_fc = (const float*)d_in[5];
    const float* b_fc = (const float*)d_in[6];
    float* out = (float*)d_out;

    const int B = in_sizes[0] / (TSZ * ISZ);  // 4096
    lstm_mfma<<<B / BTILE, NW * 64, 0, stream>>>(x, W_ih, W_hh, b_ih, b_hh, W_fc, b_fc, out);
}

// Round 3
// 334.432 us; speedup vs baseline: 7.0981x; 1.2154x over previous
//
#include <hip/hip_runtime.h>

#define HSZ 64
#define ISZ 8
#define TSZ 512
#define BTILE 16   // batch rows per block
#define NW 4       // waves per block
#define KPAD 104   // 96 K-positions + pad; 208 B row stride (16B-aligned)

typedef _Float16 f16;
typedef __attribute__((ext_vector_type(8))) _Float16 f16x8;
typedef __attribute__((ext_vector_type(4))) float f32x4;
typedef unsigned short u16;

__device__ __forceinline__ u16 f16bits(float f) {
    f16 h = (f16)f;
    union { f16 h; u16 u; } v; v.h = h;
    return v.u;
}
__device__ __forceinline__ float sigm(float x) {
    return __builtin_amdgcn_rcpf(1.0f + __builtin_amdgcn_exp2f(-1.442695041f * x));
}
__device__ __forceinline__ float tanh_(float x) {
    return fmaf(2.0f, __builtin_amdgcn_rcpf(1.0f + __builtin_amdgcn_exp2f(-2.885390082f * x)), -1.0f);
}

// block = 16 batch rows, 4 waves. Wave w owns hidden cols [16w,16w+16) for all
// 4 gates. Gates via mfma_f32_16x16x32_f16: A (h in LDS) split fp16 hi+lo,
// B (weights, registers) single fp16, x single fp16. 20 MFMA / wave / step.
// A_lds K layout: [0,64) h | [64,72) x | [72,96) zero pad.
__global__ __launch_bounds__(256) void lstm_mfma3(
    const float* __restrict__ x,      // [B, T, I]
    const float* __restrict__ W_ih,   // [4H, I]
    const float* __restrict__ W_hh,   // [4H, H]
    const float* __restrict__ b_ih,   // [4H]
    const float* __restrict__ b_hh,   // [4H]
    const float* __restrict__ W_fc,   // [O, H]
    const float* __restrict__ b_fc,   // [O]
    float* __restrict__ out)          // [B, O]
{
    const int tid = threadIdx.x;
    const int w  = tid >> 6;   // wave 0..3
    const int l  = tid & 63;
    const int lr = l & 15;     // A-row / B-col lane index
    const int lg = l >> 4;     // k-group
    const int B0 = blockIdx.x * BTILE;

    __shared__ __align__(16) u16 A_lds[2][2][BTILE][KPAD];  // [buf][hi/lo][row][k]
    __shared__ float red[NW][BTILE];

    // zero all of A_lds (pad + h(0) = 0)
    for (int i = tid; i < 2 * 2 * BTILE * KPAD; i += 256)
        ((u16*)A_lds)[i] = 0;

    // ---- B fragments (single fp16) into registers ----
    f16x8 bh[4][2];   // W_hh, k-tiles [0,32),[32,64)
    f16x8 bx[4];      // W_ih in k [64,72), zeros elsewhere
#pragma unroll
    for (int g = 0; g < 4; ++g) {
        const int row = g * HSZ + w * 16 + lr;
#pragma unroll
        for (int kt = 0; kt < 2; ++kt) {
            const float4 a = *reinterpret_cast<const float4*>(&W_hh[row * HSZ + kt * 32 + lg * 8]);
            const float4 c = *reinterpret_cast<const float4*>(&W_hh[row * HSZ + kt * 32 + lg * 8 + 4]);
            bh[g][kt][0] = (f16)a.x; bh[g][kt][1] = (f16)a.y;
            bh[g][kt][2] = (f16)a.z; bh[g][kt][3] = (f16)a.w;
            bh[g][kt][4] = (f16)c.x; bh[g][kt][5] = (f16)c.y;
            bh[g][kt][6] = (f16)c.z; bh[g][kt][7] = (f16)c.w;
        }
        if (lg == 0) {
            const float4 a = *reinterpret_cast<const float4*>(&W_ih[row * ISZ]);
            const float4 c = *reinterpret_cast<const float4*>(&W_ih[row * ISZ + 4]);
            bx[g][0] = (f16)a.x; bx[g][1] = (f16)a.y;
            bx[g][2] = (f16)a.z; bx[g][3] = (f16)a.w;
            bx[g][4] = (f16)c.x; bx[g][5] = (f16)c.y;
            bx[g][6] = (f16)c.z; bx[g][7] = (f16)c.w;
        } else {
#pragma unroll
            for (int j = 0; j < 8; ++j) bx[g][j] = (f16)0.0f;
        }
    }
    float bias[4];
#pragma unroll
    for (int g = 0; g < 4; ++g)
        bias[g] = b_ih[g * HSZ + w * 16 + lr] + b_hh[g * HSZ + w * 16 + lr];

    __syncthreads();  // zeroing visible before x staging

    // stage x(0) into buf 0 (wave 0): lane -> batch row l>>2, input pair (l&3)*2
    const int rb = l >> 2, ip = (l & 3) * 2;
    if (w == 0) {
        const float2 xv = *reinterpret_cast<const float2*>(&x[((size_t)(B0 + rb) * TSZ + 0) * ISZ + ip]);
        A_lds[0][0][rb][HSZ + ip]     = f16bits(xv.x);
        A_lds[0][0][rb][HSZ + ip + 1] = f16bits(xv.y);
    }
    __syncthreads();

    float c[4]  = {0.f, 0.f, 0.f, 0.f};
    float hv[4] = {0.f, 0.f, 0.f, 0.f};

    for (int t = 0; t < TSZ; ++t) {
        const int buf = t & 1, bufn = buf ^ 1;

        // prefetch x(t+1) (hidden under MFMA + activations)
        float2 xv = {0.f, 0.f};
        if (w == 0 && t + 1 < TSZ)
            xv = *reinterpret_cast<const float2*>(&x[((size_t)(B0 + rb) * TSZ + t + 1) * ISZ + ip]);

        // A fragments: row lr, k = base + lg*8 (16 B each)
        const f16x8 ah0 = *reinterpret_cast<const f16x8*>(&A_lds[buf][0][lr][lg * 8]);
        const f16x8 ah1 = *reinterpret_cast<const f16x8*>(&A_lds[buf][0][lr][32 + lg * 8]);
        const f16x8 al0 = *reinterpret_cast<const f16x8*>(&A_lds[buf][1][lr][lg * 8]);
        const f16x8 al1 = *reinterpret_cast<const f16x8*>(&A_lds[buf][1][lr][32 + lg * 8]);
        const f16x8 ax  = *reinterpret_cast<const f16x8*>(&A_lds[buf][0][lr][64 + lg * 8]);

        f32x4 acc[4];
#pragma unroll
        for (int g = 0; g < 4; ++g) acc[g] = f32x4{bias[g], bias[g], bias[g], bias[g]};
#pragma unroll
        for (int g = 0; g < 4; ++g) {
            acc[g] = __builtin_amdgcn_mfma_f32_16x16x32_f16(ah0, bh[g][0], acc[g], 0, 0, 0);
            acc[g] = __builtin_amdgcn_mfma_f32_16x16x32_f16(ah1, bh[g][1], acc[g], 0, 0, 0);
            acc[g] = __builtin_amdgcn_mfma_f32_16x16x32_f16(al0, bh[g][0], acc[g], 0, 0, 0);
            acc[g] = __builtin_amdgcn_mfma_f32_16x16x32_f16(al1, bh[g][1], acc[g], 0, 0, 0);
            acc[g] = __builtin_amdgcn_mfma_f32_16x16x32_f16(ax,  bx[g],    acc[g], 0, 0, 0);
        }

        // activations: lane owns (batch row = lg*4+r, hidden col = 16w+lr)
#pragma unroll
        for (int r = 0; r < 4; ++r) {
            const float ig = sigm(acc[0][r]);
            const float fg = sigm(acc[1][r]);
            const float gg = tanh_(acc[2][r]);
            const float og = sigm(acc[3][r]);
            c[r]  = fmaf(fg, c[r], ig * gg);
            hv[r] = og * tanh_(c[r]);
            const f16 hi = (f16)hv[r];
            const f16 lo = (f16)(hv[r] - (float)hi);
            union { f16 h; u16 u; } vh, vl; vh.h = hi; vl.h = lo;
            const int row = lg * 4 + r;
            A_lds[bufn][0][row][w * 16 + lr] = vh.u;
            A_lds[bufn][1][row][w * 16 + lr] = vl.u;
        }

        // store prefetched x(t+1) (single fp16, hi plane only)
        if (w == 0 && t + 1 < TSZ) {
            A_lds[bufn][0][rb][HSZ + ip]     = f16bits(xv.x);
            A_lds[bufn][0][rb][HSZ + ip + 1] = f16bits(xv.y);
        }
        __syncthreads();
    }

    // ---- final FC: out[b] = sum_hidden h * W_fc + b_fc ----
    const float wfc = W_fc[w * 16 + lr];
#pragma unroll
    for (int r = 0; r < 4; ++r) {
        float v = hv[r] * wfc;
        v += __shfl_xor(v, 1);
        v += __shfl_xor(v, 2);
        v += __shfl_xor(v, 4);
        v += __shfl_xor(v, 8);
        if (lr == 0) red[w][lg * 4 + r] = v;
    }
    __syncthreads();
    if (tid < BTILE)
        out[B0 + tid] = red[0][tid] + red[1][tid] + red[2][tid] + red[3][tid] + b_fc[0];
}

extern "C" void kernel_launch(void* const* d_in, const int* in_sizes, int n_in,
                              void* d_out, int out_size, void* d_ws, size_t ws_size,
                              hipStream_t stream) {
    const float* x    = (const float*)d_in[0];
    const float* W_ih = (const float*)d_in[1];
    const float* W_hh = (const float*)d_in[2];
    const float* b_ih = (const float*)d_in[3];
    const float* b_hh = (const float*)d_in[4];
    const float* W_fc = (const float*)d_in[5];
    const float* b_fc = (const float*)d_in[6];
    float* out = (float*)d_out;

    const int B = in_sizes[0] / (TSZ * ISZ);  // 4096
    lstm_mfma3<<<B / BTILE, NW * 64, 0, stream>>>(x, W_ih, W_hh, b_ih, b_hh, W_fc, b_fc, out);
}